// Round 16
// baseline (213.950 us; speedup 1.0000x reference)
//
#include <hip/hip_runtime.h>
#include <cstdint>
#include <cstddef>

// ---- problem constants (B=1, S=2048, H=1024, NH=16, HD=64, NT=1024) ----
#define S_LEN 2048
#define H_DIM 1024
#define NTOK  1024
#define NHEAD 16
#define HDIM  64
#define NSPLIT 2

typedef __bf16 bf16;
typedef __bf16 bf16x8 __attribute__((ext_vector_type(8)));
typedef __bf16 bf16x4 __attribute__((ext_vector_type(4)));
typedef __bf16 bf16x2 __attribute__((ext_vector_type(2)));
typedef float  f32x4  __attribute__((ext_vector_type(4)));

// 0.125 (1/sqrt(HD)) * log2(e): baked into q so softmax runs in log2 domain.
#define QSCALE_LOG2E 0.18033688011112042f

static __device__ __forceinline__ f32x4 mfma16(bf16x8 a, bf16x8 b, f32x4 c) {
    return __builtin_amdgcn_mfma_f32_16x16x32_bf16(a, b, c, 0, 0, 0);
}

static __device__ __forceinline__ void async16(const void* gp, void* lp) {
    __builtin_amdgcn_global_load_lds(
        (const __attribute__((address_space(1))) void*)gp,
        (__attribute__((address_space(3))) void*)lp, 16, 0, 0);
}

static __device__ __forceinline__ float fexp2(float x) {
    return __builtin_amdgcn_exp2f(x);
}

// one fused sync point: drain stage loads + raw barrier, no compiler extras.
// R12/R13 lesson: counted-vmcnt tri-buffering improves the GEMM locally but
// RAISES its FETCH_SIZE and the L2 pollution regresses the TOTAL. The 128x128
// tile attacks the same latency-bound stall the opposite way: +50% compute
// per staged byte and LOWER A-traffic.
#define DRAIN_BARRIER() \
    asm volatile("s_waitcnt vmcnt(0)\n\ts_barrier" ::: "memory")

// ---------------------------------------------------------------------------
// Merged prep: y<6 -> fp32->bf16 convert (1M elems each: x as 2 jobs + 4 key
// matrices); y>=6 -> fp32 1024x1024 -> transposed bf16 (4 val matrices,
// 64x64 tiles). Block (0,0) zeroes the 3x2048 QKV sum-of-squares accumulator.
// ---------------------------------------------------------------------------
struct PrepArgs {
    const float* csrc[6];
    bf16* cdst[6];
    const float* tsrc[4];
    bf16* tdst[4];
    float* ssq;  // 6144 floats, zeroed by block (0,0)
};
__global__ __launch_bounds__(256) void prep_kernel(PrepArgs a) {
    __shared__ float t[64][65];
    if (blockIdx.y < 6) {
        if (blockIdx.y == 0 && blockIdx.x == 0) {
#pragma unroll
            for (int i = 0; i < 24; ++i) a.ssq[threadIdx.x + i * 256] = 0.0f;
        }
        const float* __restrict__ s = a.csrc[blockIdx.y];
        bf16* __restrict__ d = a.cdst[blockIdx.y];
        size_t i = ((size_t)blockIdx.x * 256 + threadIdx.x) * 4;
        f32x4 v = *(const f32x4*)&s[i];
        bf16x4 o;
        o[0] = (bf16)v[0]; o[1] = (bf16)v[1]; o[2] = (bf16)v[2]; o[3] = (bf16)v[3];
        *(bf16x4*)&d[i] = o;
    } else {
        if (blockIdx.x >= 256) return;             // 16x16 tiles of 64x64
        const int z = blockIdx.y - 6;
        const float* __restrict__ in = a.tsrc[z];
        bf16* __restrict__ out = a.tdst[z];
        const int bx = (blockIdx.x & 15) * 64, by = (blockIdx.x >> 4) * 64;
        const int c4 = (threadIdx.x & 15) * 4, r0 = threadIdx.x >> 4;
#pragma unroll
        for (int rr = 0; rr < 64; rr += 16) {
            f32x4 v = *(const f32x4*)&in[(size_t)(by + r0 + rr) * 1024 + bx + c4];
#pragma unroll
            for (int j = 0; j < 4; ++j) t[c4 + j][r0 + rr] = v[j];
        }
        __syncthreads();
        const int l2 = (threadIdx.x & 31) * 2, w8 = threadIdx.x >> 5;
#pragma unroll
        for (int rr = 0; rr < 64; rr += 8) {
            int r = w8 + rr;
            bf16x2 o;
            o[0] = (bf16)t[r][l2];
            o[1] = (bf16)t[r][l2 + 1];
            *(bf16x2*)&out[(size_t)(bx + r) * 1024 + by + l2] = o;
        }
    }
}

// ---------------------------------------------------------------------------
// GEMM args. MODE 1: C = gelu(A B^T), atomically accumulate row sum-of-squares
// into S (must be pre-zeroed). MODE 2: C = A B^T * 32*rsqrt(S[row]) * emul;
// Ct != nullptr (z=2 only) => write V^T-layout (VtG) with baked chunk swizzle.
// ---------------------------------------------------------------------------
template <int MODE, typename OutT>
struct GemmArgs {
    const bf16* A[3];
    const bf16* B[3];
    OutT* C[3];
    float* S[3];
    bf16* Ct[3];
    float emul[3];
};

// ---------------------------------------------------------------------------
// GEMM: 128x128 tile, BK=64, dbuf async16 staging, XOR swizzle. 4 waves of
// 64x64 each (acc[4][4]). Grid (8,16,3)=384 blocks = up to 2/CU (64KB LDS).
// vs the 128x64 tile (R15, 51us, MfmaUtil 9%): per K-step 32 MFMA against
// 8 stage-loads/thread (was 16 vs 6) -> compute/load ratio +50%, and the
// A-panel is read by 8 column-blocks instead of 16 -> A traffic HALVES
// (FETCH down, not up -> avoids the R12/R13 L2-pollution regression).
// ---------------------------------------------------------------------------
template <int MODE, typename OutT>
__global__ __launch_bounds__(256, 2) void gemm_bt(GemmArgs<MODE, OutT> args) {
    constexpr int Kd = 1024, Nd = 1024, BK = 64;
    const bf16* __restrict__ A = args.A[blockIdx.z];
    const bf16* __restrict__ B = args.B[blockIdx.z];
    OutT* __restrict__ C = args.C[blockIdx.z];
    float* __restrict__ S = args.S[blockIdx.z];
    bf16* __restrict__ Ct = args.Ct[blockIdx.z];
    const float emul = args.emul[blockIdx.z];

    __shared__ __align__(16) bf16 As[2][128 * BK];
    __shared__ __align__(16) bf16 Bs[2][128 * BK];

    const int tid = threadIdx.x;
    const int w = tid >> 6, lane = tid & 63, quad = lane >> 4, m16 = lane & 15;
    const int wm = (w >> 1) * 64, wn = (w & 1) * 64;
    const int bm = blockIdx.y * 128, bn = blockIdx.x * 128;

    const int srow = lane >> 3;
    const int sseg = ((lane & 7) ^ srow) * 8;

    auto stage = [&](int buf, int k0) {
        const bf16* Ab = A + (size_t)bm * Kd + k0;
        const bf16* Bb = B + (size_t)bn * Kd + k0;
#pragma unroll
        for (int c = 0; c < 4; ++c) {
            int chunk = w * 4 + c;
            async16(Ab + (size_t)(chunk * 8 + srow) * Kd + sseg,
                    &As[buf][chunk * 512]);
            async16(Bb + (size_t)(chunk * 8 + srow) * Kd + sseg,
                    &Bs[buf][chunk * 512]);
        }
    };

    f32x4 acc[4][4] = {};
    stage(0, 0);

    for (int k0 = 0; k0 < Kd; k0 += BK) {
        const int buf = (k0 >> 6) & 1;
        DRAIN_BARRIER();
        if (k0 + BK < Kd) stage(buf ^ 1, k0 + BK);

        bf16x8 a[2][4], b[2][4];
#pragma unroll
        for (int kc = 0; kc < 2; ++kc) {
#pragma unroll
            for (int i = 0; i < 4; ++i) {
                int row = wm + i * 16 + m16;
                a[kc][i] = *(const bf16x8*)
                    &As[buf][row * 64 + (((kc * 4 + quad) ^ (row & 7)) << 3)];
            }
#pragma unroll
            for (int j = 0; j < 4; ++j) {
                int row = wn + j * 16 + m16;
                b[kc][j] = *(const bf16x8*)
                    &Bs[buf][row * 64 + (((kc * 4 + quad) ^ (row & 7)) << 3)];
            }
        }
#pragma unroll
        for (int kc = 0; kc < 2; ++kc)
#pragma unroll
            for (int i = 0; i < 4; ++i)
#pragma unroll
                for (int j = 0; j < 4; ++j)
                    acc[i][j] = mfma16(a[kc][i], b[kc][j], acc[i][j]);
    }

    if (MODE == 1) {
        // gelu + store + fused row sum-of-squares (norm computed from f32,
        // pre-bf16-rounding -> closer to reference than separate rowscale).
        float sq[4][4] = {};
#pragma unroll
        for (int i = 0; i < 4; ++i)
#pragma unroll
            for (int j = 0; j < 4; ++j)
#pragma unroll
                for (int r = 0; r < 4; ++r) {
                    int row = bm + wm + i * 16 + quad * 4 + r;
                    int col = bn + wn + j * 16 + m16;
                    float v = acc[i][j][r];
                    v = 0.5f * v * (1.0f + erff(v * 0.70710678118654752f));
                    C[(size_t)row * Nd + col] = (OutT)v;
                    sq[i][r] += v * v;
                }
#pragma unroll
        for (int i = 0; i < 4; ++i)
#pragma unroll
            for (int r = 0; r < 4; ++r) {
                float s2 = sq[i][r];
                s2 += __shfl_xor(s2, 1);
                s2 += __shfl_xor(s2, 2);
                s2 += __shfl_xor(s2, 4);
                s2 += __shfl_xor(s2, 8);
                if (m16 == 0)
                    atomicAdd(&S[bm + wm + i * 16 + quad * 4 + r], s2);
            }
        return;
    }

    // MODE == 2: per-row scale from fused sum-of-squares
    float scl[4][4];
#pragma unroll
    for (int i = 0; i < 4; ++i)
#pragma unroll
        for (int r = 0; r < 4; ++r)
            scl[i][r] =
                32.0f * rsqrtf(S[bm + wm + i * 16 + quad * 4 + r]) * emul;

    if (Ct != nullptr) {
        // transposed + swizzle-baked VtG write: Ct[col][k] layout, chunk
        // (k&63)>>3 stored at (chunk ^ (col&7)); 4 contiguous k per lane.
#pragma unroll
        for (int i = 0; i < 4; ++i)
#pragma unroll
            for (int j = 0; j < 4; ++j) {
                int k = bm + wm + i * 16 + quad * 4;  // base of 4 contig k
                int col = bn + wn + j * 16 + m16;     // d-index (h*64+d)
                bf16x4 o4;
#pragma unroll
                for (int r = 0; r < 4; ++r)
                    o4[r] = (bf16)(acc[i][j][r] * scl[i][r]);
                int kb = k >> 6, c = (k >> 3) & 7, off = k & 7;
                int pos = ((c ^ (col & 7)) << 3) + off;
                *(bf16x4*)&Ct[(size_t)col * 2048 + kb * 64 + pos] = o4;
            }
        return;
    }

#pragma unroll
    for (int i = 0; i < 4; ++i)
#pragma unroll
        for (int j = 0; j < 4; ++j)
#pragma unroll
            for (int r = 0; r < 4; ++r) {
                int row = bm + wm + i * 16 + quad * 4 + r;
                int col = bn + wn + j * 16 + m16;
                C[(size_t)row * Nd + col] = (OutT)(acc[i][j][r] * scl[i][r]);
            }
}

// ---------------------------------------------------------------------------
// GEMM 64x64-tile variant for the proj launches: 256 thr (4 waves of 32x32),
// grid (16,32) = 512 blocks = 2 blocks/CU. Two INDEPENDENT blocks/CU ->
// when one drains at its barrier the other computes (m114 co-scheduling).
// ---------------------------------------------------------------------------
template <int MODE, typename OutT>
__global__ __launch_bounds__(256, 2) void gemm_bt64(GemmArgs<MODE, OutT> args) {
    constexpr int Kd = 1024, Nd = 1024, BK = 64;
    const bf16* __restrict__ A = args.A[blockIdx.z];
    const bf16* __restrict__ B = args.B[blockIdx.z];
    OutT* __restrict__ C = args.C[blockIdx.z];
    float* __restrict__ S = args.S[blockIdx.z];
    const float emul = args.emul[blockIdx.z];

    __shared__ __align__(16) bf16 As[2][64 * 64];
    __shared__ __align__(16) bf16 Bs[2][64 * 64];

    const int tid = threadIdx.x;
    const int w = tid >> 6, lane = tid & 63, quad = lane >> 4, m16 = lane & 15;
    const int wm = (w >> 1) * 32, wn = (w & 1) * 32;
    const int bm = blockIdx.y * 64, bn = blockIdx.x * 64;
    const int trow = tid >> 3, t8 = (tid & 7) * 8;

    auto stage = [&](int buf, int k0) {
#pragma unroll
        for (int c = 0; c < 2; ++c) {
            int row = c * 32 + trow;
            int seg = (((tid & 7) ^ (row & 7)) << 3);
            async16(A + (size_t)(bm + row) * Kd + k0 + seg,
                    &As[buf][row * 64 + t8]);
            async16(B + (size_t)(bn + row) * Kd + k0 + seg,
                    &Bs[buf][row * 64 + t8]);
        }
    };

    f32x4 acc[2][2] = {};
    stage(0, 0);

    for (int k0 = 0; k0 < Kd; k0 += BK) {
        const int buf = (k0 >> 6) & 1;
        DRAIN_BARRIER();
        if (k0 + BK < Kd) stage(buf ^ 1, k0 + BK);

        bf16x8 a[2][2], b[2][2];
#pragma unroll
        for (int kc = 0; kc < 2; ++kc) {
#pragma unroll
            for (int i = 0; i < 2; ++i) {
                int row = wm + i * 16 + m16;
                a[kc][i] = *(const bf16x8*)
                    &As[buf][row * 64 + (((kc * 4 + quad) ^ (row & 7)) << 3)];
            }
#pragma unroll
            for (int j = 0; j < 2; ++j) {
                int row = wn + j * 16 + m16;
                b[kc][j] = *(const bf16x8*)
                    &Bs[buf][row * 64 + (((kc * 4 + quad) ^ (row & 7)) << 3)];
            }
        }
#pragma unroll
        for (int kc = 0; kc < 2; ++kc)
#pragma unroll
            for (int i = 0; i < 2; ++i)
#pragma unroll
                for (int j = 0; j < 2; ++j)
                    acc[i][j] = mfma16(a[kc][i], b[kc][j], acc[i][j]);
    }

    if (MODE == 1) {
        float sq[2][4] = {};
#pragma unroll
        for (int i = 0; i < 2; ++i)
#pragma unroll
            for (int j = 0; j < 2; ++j)
#pragma unroll
                for (int r = 0; r < 4; ++r) {
                    int row = bm + wm + i * 16 + quad * 4 + r;
                    int col = bn + wn + j * 16 + m16;
                    float v = acc[i][j][r];
                    v = 0.5f * v * (1.0f + erff(v * 0.70710678118654752f));
                    C[(size_t)row * Nd + col] = (OutT)v;
                    sq[i][r] += v * v;
                }
#pragma unroll
        for (int i = 0; i < 2; ++i)
#pragma unroll
            for (int r = 0; r < 4; ++r) {
                float s2 = sq[i][r];
                s2 += __shfl_xor(s2, 1);
                s2 += __shfl_xor(s2, 2);
                s2 += __shfl_xor(s2, 4);
                s2 += __shfl_xor(s2, 8);
                if (m16 == 0)
                    atomicAdd(&S[bm + wm + i * 16 + quad * 4 + r], s2);
            }
        return;
    }

    float scl[2][4];
#pragma unroll
    for (int i = 0; i < 2; ++i)
#pragma unroll
        for (int r = 0; r < 4; ++r)
            scl[i][r] =
                32.0f * rsqrtf(S[bm + wm + i * 16 + quad * 4 + r]) * emul;

#pragma unroll
    for (int i = 0; i < 2; ++i)
#pragma unroll
        for (int j = 0; j < 2; ++j)
#pragma unroll
            for (int r = 0; r < 4; ++r) {
                int row = bm + wm + i * 16 + quad * 4 + r;
                int col = bn + wn + j * 16 + m16;
                C[(size_t)row * Nd + col] = (OutT)(acc[i][j][r] * scl[i][r]);
            }
}

// ---------------------------------------------------------------------------
// Causal flash attention — R6/R7-proven 2-phase pipeline, NSPLIT=2:
//   per kt-step: STAGE K(i+1)+V(i+1) into LDS dbuf -> QK from Ks[cur]
//   (ds_read, swizzled) -> softmax -> PV from Vs[cur] -> fused
//   vmcnt(0)+s_barrier (stage was issued a full step ago -> near-free).
// Grid 1024 = 16h x 32qt x 2s, 3 blocks/CU (42KB LDS), qt DESCENDING so
// long blocks dispatch first. Combine-free variants (R8/R9/R10) regressed.
// Softmax in log2 domain (0.125*log2e baked into q); defer-max (T13).
// ---------------------------------------------------------------------------
struct FlashArgs {
    const bf16* Q;
    const bf16* K;
    const bf16* VtG;
    bf16* op[NSPLIT];
    float* ml;
};

__global__ __launch_bounds__(256, 3) void flash_kernel(FlashArgs fa) {
    const int bid = blockIdx.x;
    const int h = (bid & 7) * 2 + ((bid >> 3) & 1);
    const int s = (bid >> 4) & 1;
    const int qt = 31 - (bid >> 5);               // longest first
    const int tid = threadIdx.x;
    const int w = tid >> 6, lane = tid & 63, quad = lane >> 4, m16 = lane & 15;
    const int hOff = h * HDIM;

    __shared__ __align__(16) bf16 Ks[2][64 * 64];  // K tile (XOR swizzle)
    __shared__ __align__(16) bf16 Vs[2][64 * 64];  // V^T tile (baked swizzle)
    __shared__ __align__(16) bf16 Pw[4][16][72];   // per-wave P: [qrow][kcol]

    const bf16* VtH = fa.VtG + (size_t)hOff * 2048;
    bf16* __restrict__ Opart = fa.op[s];

    const int trow = tid >> 3, tseg8 = (tid & 7) * 8;

    auto stage = [&](int buf, int k0) {
#pragma unroll
        for (int c = 0; c < 2; ++c) {
            int row = c * 32 + trow;               // k-row 0..63
            int seg = (((tid & 7) ^ (row & 7)) << 3);
            async16(fa.K + (size_t)(k0 + row) * H_DIM + hOff + seg,
                    &Ks[buf][row * 64 + tseg8]);
        }
#pragma unroll
        for (int p = 0; p < 2; ++p) {
            int d = trow + p * 32;                 // d-row 0..63
            async16(VtH + (size_t)d * 2048 + k0 + tseg8,
                    &Vs[buf][d * 64 + tseg8]);
        }
    };

    const int qRow = qt * 64 + w * 16 + m16;      // this lane's q-row
    bf16x8 bq[2];
    bq[0] = *(const bf16x8*)&fa.Q[(size_t)qRow * H_DIM + hOff + quad * 8];
    bq[1] = *(const bf16x8*)&fa.Q[(size_t)qRow * H_DIM + hOff + 32 + quad * 8];

    f32x4 oacc[4] = {};   // O^T C-layout: [d-subtile jd]; row=d, col=qrow
    float m_i = -1e30f, l_i = 0.0f;

    const int cnt = (qt >= s) ? ((qt - s) >> 1) + 1 : 0;
    if (cnt > 0) {        // block-uniform branch (barriers safe)
        stage(0, s * 64);
        DRAIN_BARRIER();
    }
    for (int i = 0; i < cnt; ++i) {
        const int kt = s + i * NSPLIT;
        const int k0 = kt * 64;
        const int cur = i & 1;
        const bool diag = (kt == qt);
        // stage next tile FIRST (hides under QK+softmax+PV of this step)
        if (i + 1 < cnt) stage(cur ^ 1, (kt + NSPLIT) * 64);
        // S^T = K Q^T, K from LDS (scores in log2 domain via baked q-scale)
        f32x4 sacc[4] = {};
        __builtin_amdgcn_s_setprio(1);
#pragma unroll
        for (int ks = 0; ks < 2; ++ks)
#pragma unroll
            for (int j = 0; j < 4; ++j) {
                int row = j * 16 + m16;
                bf16x8 ak = *(const bf16x8*)
                    &Ks[cur][row * 64 + (((ks * 4 + quad) ^ (row & 7)) << 3)];
                sacc[j] = mfma16(ak, bq[ks], sacc[j]);
            }
        __builtin_amdgcn_s_setprio(0);
        // causal mask in-place, then tree-max (depth 4)
        if (diag) {
#pragma unroll
            for (int j = 0; j < 4; ++j)
#pragma unroll
                for (int rr = 0; rr < 4; ++rr) {
                    int kcol = k0 + j * 16 + quad * 4 + rr;
                    if (kcol > qRow) sacc[j][rr] = -1e30f;
                }
        }
        float tj[4];
#pragma unroll
        for (int j = 0; j < 4; ++j)
            tj[j] = fmaxf(fmaxf(sacc[j][0], sacc[j][1]),
                          fmaxf(sacc[j][2], sacc[j][3]));
        float mx = fmaxf(fmaxf(tj[0], tj[1]), fmaxf(tj[2], tj[3]));
        mx = fmaxf(mx, __shfl_xor(mx, 16));
        mx = fmaxf(mx, __shfl_xor(mx, 32));
        // defer-max: only rescale when the running max grew materially
        if (!__all(mx - m_i <= 11.5f)) {
            float mnew = fmaxf(m_i, mx);
            float alpha = fexp2(m_i - mnew);
            l_i *= alpha;
#pragma unroll
            for (int jd = 0; jd < 4; ++jd)
#pragma unroll
                for (int rr = 0; rr < 4; ++rr) oacc[jd][rr] *= alpha;
            m_i = mnew;
        }
        float lsj[4];
#pragma unroll
        for (int j = 0; j < 4; ++j) {
            bf16x4 pk;
            float p0 = fexp2(sacc[j][0] - m_i);
            float p1 = fexp2(sacc[j][1] - m_i);
            float p2 = fexp2(sacc[j][2] - m_i);
            float p3 = fexp2(sacc[j][3] - m_i);
            pk[0] = (bf16)p0; pk[1] = (bf16)p1;
            pk[2] = (bf16)p2; pk[3] = (bf16)p3;
            lsj[j] = (p0 + p1) + (p2 + p3);
            *(bf16x4*)&Pw[w][m16][j * 16 + quad * 4] = pk;
        }
        float ls = (lsj[0] + lsj[1]) + (lsj[2] + lsj[3]);
        ls += __shfl_xor(ls, 16);
        ls += __shfl_xor(ls, 32);
        l_i += ls;
        // O^T += V^T P^T  (Pw is wave-local; compiler orders its lgkm)
        __builtin_amdgcn_s_setprio(1);
#pragma unroll
        for (int ks = 0; ks < 2; ++ks) {
            bf16x8 bp = *(const bf16x8*)&Pw[w][m16][ks * 32 + quad * 8];
#pragma unroll
            for (int jd = 0; jd < 4; ++jd) {
                int d = jd * 16 + m16;
                bf16x8 av = *(const bf16x8*)
                    &Vs[cur][d * 64 + (((ks * 4 + quad) ^ (d & 7)) << 3)];
                oacc[jd] = mfma16(av, bp, oacc[jd]);
            }
        }
        __builtin_amdgcn_s_setprio(0);
        DRAIN_BARRIER();
    }
#pragma unroll
    for (int jd = 0; jd < 4; ++jd) {
        bf16x4 o4;
#pragma unroll
        for (int rr = 0; rr < 4; ++rr) o4[rr] = (bf16)oacc[jd][rr];
        *(bf16x4*)&Opart[(size_t)qRow * 1024 + hOff + jd * 16 + quad * 4] = o4;
    }
    if (quad == 0) {
        float* p = fa.ml + ((size_t)(s * 2048 + qRow) * 16 + h) * 2;
        p[0] = m_i;   // log2 domain
        p[1] = l_i;
    }
}

// ---------------------------------------------------------------------------
// Combine the split partials: one wave per (row, head), lane = d.
// m/l are in log2 domain -> exp2. Blocks 0..7 also zero the proj
// sum-of-squares accumulator (region dead between g1 and p1).
// ---------------------------------------------------------------------------
struct CombArgs {
    const bf16* op[NSPLIT];
    const float* ml;
    bf16* ctx;
    float* ssp;  // 2048 floats, zeroed by blocks 0..7
};
__global__ __launch_bounds__(256) void combine_kernel(CombArgs ca) {
    if (blockIdx.x < 8) ca.ssp[blockIdx.x * 256 + threadIdx.x] = 0.0f;
    const int unit = blockIdx.x * 4 + (threadIdx.x >> 6);
    const int row = unit >> 4, h = unit & 15;
    const int d = threadIdx.x & 63;
    float mv[NSPLIT], lv[NSPLIT], M = -1e30f;
#pragma unroll
    for (int s2 = 0; s2 < NSPLIT; ++s2) {
        const float* p = ca.ml + ((size_t)(s2 * 2048 + row) * 16 + h) * 2;
        mv[s2] = p[0];
        lv[s2] = p[1];
        M = fmaxf(M, mv[s2]);
    }
    float num = 0.0f, den = 0.0f;
#pragma unroll
    for (int s2 = 0; s2 < NSPLIT; ++s2) {
        float e = fexp2(mv[s2] - M);
        den += lv[s2] * e;
        num += e * (float)ca.op[s2][(size_t)row * 1024 + h * 64 + d];
    }
    ca.ctx[(size_t)row * 1024 + h * 64 + d] = (bf16)(num / den);
}

// ---------------------------------------------------------------------------
// Orchestration. Inputs/outputs FLOAT32 per the reference. 7 launches:
// prep -> g1 -> g2 -> flash -> combine -> p1 -> p2.
// ws layout (40 MB, phase-aliased):
//   0..4M    xb -> qb                16..24M  kb16[0..3] (kb16[3]=proj key)
//   4..12M   g3[0,1] -> Opart s0,s1  24..32M  vT16[0..3] (vT16[3]=proj val)
//   12..16M  g3[2] (dead post-g2)
//   20..21M  kb16[2] (dead) -> ml    21..21M+8K  SSp (zeroed by combine)
//   32..36M  kbuf -> ctx             36..40M  VtG (g2 z=2 epilogue)
//   projg aliases 4..8M after combine.
// SSq (3x2048 f32) lives in d_out (dead until p2 writes), zeroed by prep.
// ---------------------------------------------------------------------------
extern "C" void kernel_launch(void* const* d_in, const int* in_sizes, int n_in,
                              void* d_out, int out_size, void* d_ws,
                              size_t ws_size, hipStream_t stream) {
    const float* x = (const float*)d_in[0];
    const float* keysF[4] = {(const float*)d_in[1], (const float*)d_in[3],
                             (const float*)d_in[5], (const float*)d_in[7]};
    const float* valsF[4] = {(const float*)d_in[2], (const float*)d_in[4],
                             (const float*)d_in[6], (const float*)d_in[8]};
    float* out = (float*)d_out;

    char* ws = (char*)d_ws;
    bf16* xb = (bf16*)(ws);
    bf16* g3[3];
    for (int i = 0; i < 3; ++i) g3[i] = (bf16*)(ws + (4ull << 20) + (size_t)i * (4ull << 20));
    bf16* kb16[4], *vT16[4];
    for (int i = 0; i < 4; ++i) {
        kb16[i] = (bf16*)(ws + (16ull << 20) + (size_t)i * (2ull << 20));
        vT16[i] = (bf16*)(ws + (24ull << 20) + (size_t)i * (2ull << 20));
    }
    bf16* qb    = (bf16*)(ws);
    bf16* kbuf  = (bf16*)(ws + (32ull << 20));
    float* mlbuf = (float*)(ws + (20ull << 20));
    bf16* VtG   = (bf16*)(ws + (36ull << 20));
    bf16* ctx   = (bf16*)(ws + (32ull << 20));
    bf16* projg = (bf16*)(ws + (4ull << 20));

    float* SSq = (float*)d_out;                 // 3x2048 f32 (out: dead til p2)
    float* SSp = (float*)(ws + (21ull << 20));  // 2048 f32 (dead zone 21..22M)

    bf16* opart[NSPLIT];
    for (int i = 0; i < NSPLIT; ++i)
        opart[i] = (bf16*)(ws + (4ull << 20) + (size_t)i * (4ull << 20));

    // 1. merged prep: convert x + 4 keys; transpose+convert 4 vals; zero SSq
    PrepArgs pa;
    pa.csrc[0] = x;             pa.cdst[0] = xb;
    pa.csrc[1] = x + (1 << 20); pa.cdst[1] = xb + (1 << 20);
    for (int i = 0; i < 4; ++i) { pa.csrc[2 + i] = keysF[i]; pa.cdst[2 + i] = kb16[i]; }
    for (int i = 0; i < 4; ++i) { pa.tsrc[i] = valsF[i]; pa.tdst[i] = vT16[i]; }
    pa.ssq = SSq;
    prep_kernel<<<dim3(1024, 10), 256, 0, stream>>>(pa);

    // 2. batched QKV: g = gelu(x @ key^T), fused row sum-of-squares -> SSq
    GemmArgs<1, bf16> g1;
    for (int z = 0; z < 3; ++z) {
        g1.A[z] = xb; g1.B[z] = kb16[z]; g1.C[z] = g3[z];
        g1.S[z] = SSq + z * 2048; g1.Ct[z] = nullptr; g1.emul[z] = 1.0f;
    }
    gemm_bt<1, bf16><<<dim3(8, 16, 3), 256, 0, stream>>>(g1);

    // 3. batched: q (with 0.125*log2e baked in), k row-major; V written
    //    directly transposed+swizzled (VtG). Scale = 32*rsqrt(SSq[row]).
    GemmArgs<2, bf16> g2;
    bf16* qkv[3] = {qb, kbuf, qb /*unused for z=2*/};
    for (int z = 0; z < 3; ++z) {
        g2.A[z] = g3[z]; g2.B[z] = vT16[z]; g2.C[z] = qkv[z];
        g2.S[z] = SSq + z * 2048;
        g2.Ct[z] = (z == 2) ? VtG : nullptr;
        g2.emul[z] = (z == 0) ? QSCALE_LOG2E : 1.0f;
    }
    gemm_bt<2, bf16><<<dim3(8, 16, 3), 256, 0, stream>>>(g2);

    // 4. flash attention: 1024 blocks x 256 thr, 2-phase pipelined LDS
    FlashArgs fla;
    fla.Q = qb; fla.K = kbuf; fla.VtG = VtG; fla.ml = mlbuf;
    for (int i = 0; i < NSPLIT; ++i) fla.op[i] = opart[i];
    flash_kernel<<<dim3(1024), 256, 0, stream>>>(fla);

    // 5. combine split partials -> ctx (also zeroes SSp)
    CombArgs cba;
    for (int i = 0; i < NSPLIT; ++i) cba.op[i] = opart[i];
    cba.ml = mlbuf; cba.ctx = ctx; cba.ssp = SSp;
    combine_kernel<<<dim3(8192), 256, 0, stream>>>(cba);

    // 6-7. output projection pattention (64x64-tile GEMMs, 2 blocks/CU)
    GemmArgs<1, bf16> p1;
    for (int z = 0; z < 3; ++z) {
        p1.A[z] = ctx; p1.B[z] = kb16[3]; p1.C[z] = projg;
        p1.S[z] = SSp; p1.Ct[z] = nullptr; p1.emul[z] = 1.0f;
    }
    gemm_bt64<1, bf16><<<dim3(16, 32, 1), 256, 0, stream>>>(p1);

    GemmArgs<2, float> p2;
    for (int z = 0; z < 3; ++z) {
        p2.A[z] = projg; p2.B[z] = vT16[3]; p2.C[z] = out;
        p2.S[z] = SSp; p2.Ct[z] = nullptr; p2.emul[z] = 1.0f;
    }
    gemm_bt64<2, float><<<dim3(16, 32, 1), 256, 0, stream>>>(p2);
}

// Round 17
// 207.928 us; speedup vs baseline: 1.0290x; 1.0290x over previous
//
#include <hip/hip_runtime.h>
#include <cstdint>
#include <cstddef>

// ---- problem constants (B=1, S=2048, H=1024, NH=16, HD=64, NT=1024) ----
#define S_LEN 2048
#define H_DIM 1024
#define NTOK  1024
#define NHEAD 16
#define HDIM  64
#define NSPLIT 2

typedef __bf16 bf16;
typedef __bf16 bf16x8 __attribute__((ext_vector_type(8)));
typedef __bf16 bf16x4 __attribute__((ext_vector_type(4)));
typedef __bf16 bf16x2 __attribute__((ext_vector_type(2)));
typedef float  f32x4  __attribute__((ext_vector_type(4)));

// 0.125 (1/sqrt(HD)) * log2(e): baked into q so softmax runs in log2 domain.
#define QSCALE_LOG2E 0.18033688011112042f

static __device__ __forceinline__ f32x4 mfma16(bf16x8 a, bf16x8 b, f32x4 c) {
    return __builtin_amdgcn_mfma_f32_16x16x32_bf16(a, b, c, 0, 0, 0);
}

static __device__ __forceinline__ void async16(const void* gp, void* lp) {
    __builtin_amdgcn_global_load_lds(
        (const __attribute__((address_space(1))) void*)gp,
        (__attribute__((address_space(3))) void*)lp, 16, 0, 0);
}

static __device__ __forceinline__ float fexp2(float x) {
    return __builtin_amdgcn_exp2f(x);
}

// one fused sync point: drain stage loads + raw barrier, no compiler extras.
// Session-verified lessons baked into this config:
//  - R12/R13: tri-buffer+counted-vmcnt wins locally (-5us) but doubles GEMM
//    FETCH -> L2 pollution regresses TOTAL (+13-18us).
//  - R16: 128x128 tile wins locally (<=43us) but 2 blocks/CU + worse tail
//    regresses TOTAL (+6us).
//  - R8-R10: combine-free flash variants all regressed.
// This dbuf/128x64/3-blocks-CU + NSPLIT=2 flash config measured 208.3us.
#define DRAIN_BARRIER() \
    asm volatile("s_waitcnt vmcnt(0)\n\ts_barrier" ::: "memory")

// ---------------------------------------------------------------------------
// Merged prep: y<6 -> fp32->bf16 convert (1M elems each: x as 2 jobs + 4 key
// matrices); y>=6 -> fp32 1024x1024 -> transposed bf16 (4 val matrices,
// 64x64 tiles). Block (0,0) zeroes the 3x2048 QKV sum-of-squares accumulator.
// ---------------------------------------------------------------------------
struct PrepArgs {
    const float* csrc[6];
    bf16* cdst[6];
    const float* tsrc[4];
    bf16* tdst[4];
    float* ssq;  // 6144 floats, zeroed by block (0,0)
};
__global__ __launch_bounds__(256) void prep_kernel(PrepArgs a) {
    __shared__ float t[64][65];
    if (blockIdx.y < 6) {
        if (blockIdx.y == 0 && blockIdx.x == 0) {
#pragma unroll
            for (int i = 0; i < 24; ++i) a.ssq[threadIdx.x + i * 256] = 0.0f;
        }
        const float* __restrict__ s = a.csrc[blockIdx.y];
        bf16* __restrict__ d = a.cdst[blockIdx.y];
        size_t i = ((size_t)blockIdx.x * 256 + threadIdx.x) * 4;
        f32x4 v = *(const f32x4*)&s[i];
        bf16x4 o;
        o[0] = (bf16)v[0]; o[1] = (bf16)v[1]; o[2] = (bf16)v[2]; o[3] = (bf16)v[3];
        *(bf16x4*)&d[i] = o;
    } else {
        if (blockIdx.x >= 256) return;             // 16x16 tiles of 64x64
        const int z = blockIdx.y - 6;
        const float* __restrict__ in = a.tsrc[z];
        bf16* __restrict__ out = a.tdst[z];
        const int bx = (blockIdx.x & 15) * 64, by = (blockIdx.x >> 4) * 64;
        const int c4 = (threadIdx.x & 15) * 4, r0 = threadIdx.x >> 4;
#pragma unroll
        for (int rr = 0; rr < 64; rr += 16) {
            f32x4 v = *(const f32x4*)&in[(size_t)(by + r0 + rr) * 1024 + bx + c4];
#pragma unroll
            for (int j = 0; j < 4; ++j) t[c4 + j][r0 + rr] = v[j];
        }
        __syncthreads();
        const int l2 = (threadIdx.x & 31) * 2, w8 = threadIdx.x >> 5;
#pragma unroll
        for (int rr = 0; rr < 64; rr += 8) {
            int r = w8 + rr;
            bf16x2 o;
            o[0] = (bf16)t[r][l2];
            o[1] = (bf16)t[r][l2 + 1];
            *(bf16x2*)&out[(size_t)(bx + r) * 1024 + by + l2] = o;
        }
    }
}

// ---------------------------------------------------------------------------
// GEMM args. MODE 1: C = gelu(A B^T), atomically accumulate row sum-of-squares
// into S (must be pre-zeroed). MODE 2: C = A B^T * 32*rsqrt(S[row]) * emul;
// Ct != nullptr (z=2 only) => write V^T-layout (VtG) with baked chunk swizzle.
// ---------------------------------------------------------------------------
template <int MODE, typename OutT>
struct GemmArgs {
    const bf16* A[3];
    const bf16* B[3];
    OutT* C[3];
    float* S[3];
    bf16* Ct[3];
    float emul[3];
};

// ---------------------------------------------------------------------------
// GEMM (R7/R15-proven, 208.3us config): 128x64 tile, BK=64, DOUBLE-buffered
// async16 staging, XOR swizzle. 4 waves x (64x32). 768 blocks (z=3) =
// 3/CU at (256,3). Fused vmcnt+s_barrier per K-step.
// ---------------------------------------------------------------------------
template <int MODE, typename OutT>
__global__ __launch_bounds__(256, 3) void gemm_bt(GemmArgs<MODE, OutT> args) {
    constexpr int Kd = 1024, Nd = 1024, BK = 64;
    const bf16* __restrict__ A = args.A[blockIdx.z];
    const bf16* __restrict__ B = args.B[blockIdx.z];
    OutT* __restrict__ C = args.C[blockIdx.z];
    float* __restrict__ S = args.S[blockIdx.z];
    bf16* __restrict__ Ct = args.Ct[blockIdx.z];
    const float emul = args.emul[blockIdx.z];

    __shared__ __align__(16) bf16 As[2][128 * BK];
    __shared__ __align__(16) bf16 Bs[2][64 * BK];

    const int tid = threadIdx.x;
    const int w = tid >> 6, lane = tid & 63, quad = lane >> 4, m16 = lane & 15;
    const int wm = (w >> 1) * 64, wn = (w & 1) * 32;
    const int bm = blockIdx.y * 128, bn = blockIdx.x * 64;

    const int srow = lane >> 3;
    const int sseg = ((lane & 7) ^ srow) * 8;

    auto stage = [&](int buf, int k0) {
        const bf16* Ab = A + (size_t)bm * Kd + k0;
#pragma unroll
        for (int c = 0; c < 4; ++c) {
            int chunk = w * 4 + c;
            async16(Ab + (size_t)(chunk * 8 + srow) * Kd + sseg,
                    &As[buf][chunk * 512]);
        }
        const bf16* Bb = B + (size_t)bn * Kd + k0;
#pragma unroll
        for (int c = 0; c < 2; ++c) {
            int chunk = w * 2 + c;
            async16(Bb + (size_t)(chunk * 8 + srow) * Kd + sseg,
                    &Bs[buf][chunk * 512]);
        }
    };

    f32x4 acc[4][2] = {};
    stage(0, 0);

    for (int k0 = 0; k0 < Kd; k0 += BK) {
        const int buf = (k0 >> 6) & 1;
        DRAIN_BARRIER();
        if (k0 + BK < Kd) stage(buf ^ 1, k0 + BK);

        bf16x8 a[2][4], b[2][2];
#pragma unroll
        for (int kc = 0; kc < 2; ++kc) {
#pragma unroll
            for (int i = 0; i < 4; ++i) {
                int row = wm + i * 16 + m16;
                a[kc][i] = *(const bf16x8*)
                    &As[buf][row * 64 + (((kc * 4 + quad) ^ (row & 7)) << 3)];
            }
#pragma unroll
            for (int j = 0; j < 2; ++j) {
                int row = wn + j * 16 + m16;
                b[kc][j] = *(const bf16x8*)
                    &Bs[buf][row * 64 + (((kc * 4 + quad) ^ (row & 7)) << 3)];
            }
        }
#pragma unroll
        for (int kc = 0; kc < 2; ++kc)
#pragma unroll
            for (int i = 0; i < 4; ++i)
#pragma unroll
                for (int j = 0; j < 2; ++j)
                    acc[i][j] = mfma16(a[kc][i], b[kc][j], acc[i][j]);
    }

    if (MODE == 1) {
        // gelu + store + fused row sum-of-squares (norm computed from f32,
        // pre-bf16-rounding -> closer to reference than separate rowscale).
        float sq[4][4] = {};
#pragma unroll
        for (int i = 0; i < 4; ++i)
#pragma unroll
            for (int j = 0; j < 2; ++j)
#pragma unroll
                for (int r = 0; r < 4; ++r) {
                    int row = bm + wm + i * 16 + quad * 4 + r;
                    int col = bn + wn + j * 16 + m16;
                    float v = acc[i][j][r];
                    v = 0.5f * v * (1.0f + erff(v * 0.70710678118654752f));
                    C[(size_t)row * Nd + col] = (OutT)v;
                    sq[i][r] += v * v;
                }
#pragma unroll
        for (int i = 0; i < 4; ++i)
#pragma unroll
            for (int r = 0; r < 4; ++r) {
                float s2 = sq[i][r];
                s2 += __shfl_xor(s2, 1);
                s2 += __shfl_xor(s2, 2);
                s2 += __shfl_xor(s2, 4);
                s2 += __shfl_xor(s2, 8);
                if (m16 == 0)
                    atomicAdd(&S[bm + wm + i * 16 + quad * 4 + r], s2);
            }
        return;
    }

    // MODE == 2: per-row scale from fused sum-of-squares
    float scl[4][4];
#pragma unroll
    for (int i = 0; i < 4; ++i)
#pragma unroll
        for (int r = 0; r < 4; ++r)
            scl[i][r] =
                32.0f * rsqrtf(S[bm + wm + i * 16 + quad * 4 + r]) * emul;

    if (Ct != nullptr) {
        // transposed + swizzle-baked VtG write: Ct[col][k] layout, chunk
        // (k&63)>>3 stored at (chunk ^ (col&7)); 4 contiguous k per lane.
#pragma unroll
        for (int i = 0; i < 4; ++i)
#pragma unroll
            for (int j = 0; j < 2; ++j) {
                int k = bm + wm + i * 16 + quad * 4;  // base of 4 contig k
                int col = bn + wn + j * 16 + m16;     // d-index (h*64+d)
                bf16x4 o4;
#pragma unroll
                for (int r = 0; r < 4; ++r)
                    o4[r] = (bf16)(acc[i][j][r] * scl[i][r]);
                int kb = k >> 6, c = (k >> 3) & 7, off = k & 7;
                int pos = ((c ^ (col & 7)) << 3) + off;
                *(bf16x4*)&Ct[(size_t)col * 2048 + kb * 64 + pos] = o4;
            }
        return;
    }

#pragma unroll
    for (int i = 0; i < 4; ++i)
#pragma unroll
        for (int j = 0; j < 2; ++j)
#pragma unroll
            for (int r = 0; r < 4; ++r) {
                int row = bm + wm + i * 16 + quad * 4 + r;
                int col = bn + wn + j * 16 + m16;
                C[(size_t)row * Nd + col] = (OutT)(acc[i][j][r] * scl[i][r]);
            }
}

// ---------------------------------------------------------------------------
// GEMM 64x64-tile variant for the proj launches: 256 thr (4 waves of 32x32),
// grid (16,32) = 512 blocks = 2 blocks/CU. Two INDEPENDENT blocks/CU ->
// when one drains at its barrier the other computes (m114 co-scheduling).
// ---------------------------------------------------------------------------
template <int MODE, typename OutT>
__global__ __launch_bounds__(256, 2) void gemm_bt64(GemmArgs<MODE, OutT> args) {
    constexpr int Kd = 1024, Nd = 1024, BK = 64;
    const bf16* __restrict__ A = args.A[blockIdx.z];
    const bf16* __restrict__ B = args.B[blockIdx.z];
    OutT* __restrict__ C = args.C[blockIdx.z];
    float* __restrict__ S = args.S[blockIdx.z];
    const float emul = args.emul[blockIdx.z];

    __shared__ __align__(16) bf16 As[2][64 * 64];
    __shared__ __align__(16) bf16 Bs[2][64 * 64];

    const int tid = threadIdx.x;
    const int w = tid >> 6, lane = tid & 63, quad = lane >> 4, m16 = lane & 15;
    const int wm = (w >> 1) * 32, wn = (w & 1) * 32;
    const int bm = blockIdx.y * 64, bn = blockIdx.x * 64;
    const int trow = tid >> 3, t8 = (tid & 7) * 8;

    auto stage = [&](int buf, int k0) {
#pragma unroll
        for (int c = 0; c < 2; ++c) {
            int row = c * 32 + trow;
            int seg = (((tid & 7) ^ (row & 7)) << 3);
            async16(A + (size_t)(bm + row) * Kd + k0 + seg,
                    &As[buf][row * 64 + t8]);
            async16(B + (size_t)(bn + row) * Kd + k0 + seg,
                    &Bs[buf][row * 64 + t8]);
        }
    };

    f32x4 acc[2][2] = {};
    stage(0, 0);

    for (int k0 = 0; k0 < Kd; k0 += BK) {
        const int buf = (k0 >> 6) & 1;
        DRAIN_BARRIER();
        if (k0 + BK < Kd) stage(buf ^ 1, k0 + BK);

        bf16x8 a[2][2], b[2][2];
#pragma unroll
        for (int kc = 0; kc < 2; ++kc) {
#pragma unroll
            for (int i = 0; i < 2; ++i) {
                int row = wm + i * 16 + m16;
                a[kc][i] = *(const bf16x8*)
                    &As[buf][row * 64 + (((kc * 4 + quad) ^ (row & 7)) << 3)];
            }
#pragma unroll
            for (int j = 0; j < 2; ++j) {
                int row = wn + j * 16 + m16;
                b[kc][j] = *(const bf16x8*)
                    &Bs[buf][row * 64 + (((kc * 4 + quad) ^ (row & 7)) << 3)];
            }
        }
#pragma unroll
        for (int kc = 0; kc < 2; ++kc)
#pragma unroll
            for (int i = 0; i < 2; ++i)
#pragma unroll
                for (int j = 0; j < 2; ++j)
                    acc[i][j] = mfma16(a[kc][i], b[kc][j], acc[i][j]);
    }

    if (MODE == 1) {
        float sq[2][4] = {};
#pragma unroll
        for (int i = 0; i < 2; ++i)
#pragma unroll
            for (int j = 0; j < 2; ++j)
#pragma unroll
                for (int r = 0; r < 4; ++r) {
                    int row = bm + wm + i * 16 + quad * 4 + r;
                    int col = bn + wn + j * 16 + m16;
                    float v = acc[i][j][r];
                    v = 0.5f * v * (1.0f + erff(v * 0.70710678118654752f));
                    C[(size_t)row * Nd + col] = (OutT)v;
                    sq[i][r] += v * v;
                }
#pragma unroll
        for (int i = 0; i < 2; ++i)
#pragma unroll
            for (int r = 0; r < 4; ++r) {
                float s2 = sq[i][r];
                s2 += __shfl_xor(s2, 1);
                s2 += __shfl_xor(s2, 2);
                s2 += __shfl_xor(s2, 4);
                s2 += __shfl_xor(s2, 8);
                if (m16 == 0)
                    atomicAdd(&S[bm + wm + i * 16 + quad * 4 + r], s2);
            }
        return;
    }

    float scl[2][4];
#pragma unroll
    for (int i = 0; i < 2; ++i)
#pragma unroll
        for (int r = 0; r < 4; ++r)
            scl[i][r] =
                32.0f * rsqrtf(S[bm + wm + i * 16 + quad * 4 + r]) * emul;

#pragma unroll
    for (int i = 0; i < 2; ++i)
#pragma unroll
        for (int j = 0; j < 2; ++j)
#pragma unroll
            for (int r = 0; r < 4; ++r) {
                int row = bm + wm + i * 16 + quad * 4 + r;
                int col = bn + wn + j * 16 + m16;
                C[(size_t)row * Nd + col] = (OutT)(acc[i][j][r] * scl[i][r]);
            }
}

// ---------------------------------------------------------------------------
// Causal flash attention — R6/R7-proven 2-phase pipeline, NSPLIT=2:
//   per kt-step: STAGE K(i+1)+V(i+1) into LDS dbuf -> QK from Ks[cur]
//   (ds_read, swizzled) -> softmax -> PV from Vs[cur] -> fused
//   vmcnt(0)+s_barrier (stage was issued a full step ago -> near-free).
// Grid 1024 = 16h x 32qt x 2s, 3 blocks/CU (42KB LDS), qt DESCENDING so
// long blocks dispatch first. Combine-free variants (R8/R9/R10) regressed.
// Softmax in log2 domain (0.125*log2e baked into q); defer-max (T13).
// ---------------------------------------------------------------------------
struct FlashArgs {
    const bf16* Q;
    const bf16* K;
    const bf16* VtG;
    bf16* op[NSPLIT];
    float* ml;
};

__global__ __launch_bounds__(256, 3) void flash_kernel(FlashArgs fa) {
    const int bid = blockIdx.x;
    const int h = (bid & 7) * 2 + ((bid >> 3) & 1);
    const int s = (bid >> 4) & 1;
    const int qt = 31 - (bid >> 5);               // longest first
    const int tid = threadIdx.x;
    const int w = tid >> 6, lane = tid & 63, quad = lane >> 4, m16 = lane & 15;
    const int hOff = h * HDIM;

    __shared__ __align__(16) bf16 Ks[2][64 * 64];  // K tile (XOR swizzle)
    __shared__ __align__(16) bf16 Vs[2][64 * 64];  // V^T tile (baked swizzle)
    __shared__ __align__(16) bf16 Pw[4][16][72];   // per-wave P: [qrow][kcol]

    const bf16* VtH = fa.VtG + (size_t)hOff * 2048;
    bf16* __restrict__ Opart = fa.op[s];

    const int trow = tid >> 3, tseg8 = (tid & 7) * 8;

    auto stage = [&](int buf, int k0) {
#pragma unroll
        for (int c = 0; c < 2; ++c) {
            int row = c * 32 + trow;               // k-row 0..63
            int seg = (((tid & 7) ^ (row & 7)) << 3);
            async16(fa.K + (size_t)(k0 + row) * H_DIM + hOff + seg,
                    &Ks[buf][row * 64 + tseg8]);
        }
#pragma unroll
        for (int p = 0; p < 2; ++p) {
            int d = trow + p * 32;                 // d-row 0..63
            async16(VtH + (size_t)d * 2048 + k0 + tseg8,
                    &Vs[buf][d * 64 + tseg8]);
        }
    };

    const int qRow = qt * 64 + w * 16 + m16;      // this lane's q-row
    bf16x8 bq[2];
    bq[0] = *(const bf16x8*)&fa.Q[(size_t)qRow * H_DIM + hOff + quad * 8];
    bq[1] = *(const bf16x8*)&fa.Q[(size_t)qRow * H_DIM + hOff + 32 + quad * 8];

    f32x4 oacc[4] = {};   // O^T C-layout: [d-subtile jd]; row=d, col=qrow
    float m_i = -1e30f, l_i = 0.0f;

    const int cnt = (qt >= s) ? ((qt - s) >> 1) + 1 : 0;
    if (cnt > 0) {        // block-uniform branch (barriers safe)
        stage(0, s * 64);
        DRAIN_BARRIER();
    }
    for (int i = 0; i < cnt; ++i) {
        const int kt = s + i * NSPLIT;
        const int k0 = kt * 64;
        const int cur = i & 1;
        const bool diag = (kt == qt);
        // stage next tile FIRST (hides under QK+softmax+PV of this step)
        if (i + 1 < cnt) stage(cur ^ 1, (kt + NSPLIT) * 64);
        // S^T = K Q^T, K from LDS (scores in log2 domain via baked q-scale)
        f32x4 sacc[4] = {};
        __builtin_amdgcn_s_setprio(1);
#pragma unroll
        for (int ks = 0; ks < 2; ++ks)
#pragma unroll
            for (int j = 0; j < 4; ++j) {
                int row = j * 16 + m16;
                bf16x8 ak = *(const bf16x8*)
                    &Ks[cur][row * 64 + (((ks * 4 + quad) ^ (row & 7)) << 3)];
                sacc[j] = mfma16(ak, bq[ks], sacc[j]);
            }
        __builtin_amdgcn_s_setprio(0);
        // causal mask in-place, then tree-max (depth 4)
        if (diag) {
#pragma unroll
            for (int j = 0; j < 4; ++j)
#pragma unroll
                for (int rr = 0; rr < 4; ++rr) {
                    int kcol = k0 + j * 16 + quad * 4 + rr;
                    if (kcol > qRow) sacc[j][rr] = -1e30f;
                }
        }
        float tj[4];
#pragma unroll
        for (int j = 0; j < 4; ++j)
            tj[j] = fmaxf(fmaxf(sacc[j][0], sacc[j][1]),
                          fmaxf(sacc[j][2], sacc[j][3]));
        float mx = fmaxf(fmaxf(tj[0], tj[1]), fmaxf(tj[2], tj[3]));
        mx = fmaxf(mx, __shfl_xor(mx, 16));
        mx = fmaxf(mx, __shfl_xor(mx, 32));
        // defer-max: only rescale when the running max grew materially
        if (!__all(mx - m_i <= 11.5f)) {
            float mnew = fmaxf(m_i, mx);
            float alpha = fexp2(m_i - mnew);
            l_i *= alpha;
#pragma unroll
            for (int jd = 0; jd < 4; ++jd)
#pragma unroll
                for (int rr = 0; rr < 4; ++rr) oacc[jd][rr] *= alpha;
            m_i = mnew;
        }
        float lsj[4];
#pragma unroll
        for (int j = 0; j < 4; ++j) {
            bf16x4 pk;
            float p0 = fexp2(sacc[j][0] - m_i);
            float p1 = fexp2(sacc[j][1] - m_i);
            float p2 = fexp2(sacc[j][2] - m_i);
            float p3 = fexp2(sacc[j][3] - m_i);
            pk[0] = (bf16)p0; pk[1] = (bf16)p1;
            pk[2] = (bf16)p2; pk[3] = (bf16)p3;
            lsj[j] = (p0 + p1) + (p2 + p3);
            *(bf16x4*)&Pw[w][m16][j * 16 + quad * 4] = pk;
        }
        float ls = (lsj[0] + lsj[1]) + (lsj[2] + lsj[3]);
        ls += __shfl_xor(ls, 16);
        ls += __shfl_xor(ls, 32);
        l_i += ls;
        // O^T += V^T P^T  (Pw is wave-local; compiler orders its lgkm)
        __builtin_amdgcn_s_setprio(1);
#pragma unroll
        for (int ks = 0; ks < 2; ++ks) {
            bf16x8 bp = *(const bf16x8*)&Pw[w][m16][ks * 32 + quad * 8];
#pragma unroll
            for (int jd = 0; jd < 4; ++jd) {
                int d = jd * 16 + m16;
                bf16x8 av = *(const bf16x8*)
                    &Vs[cur][d * 64 + (((ks * 4 + quad) ^ (d & 7)) << 3)];
                oacc[jd] = mfma16(av, bp, oacc[jd]);
            }
        }
        __builtin_amdgcn_s_setprio(0);
        DRAIN_BARRIER();
    }
#pragma unroll
    for (int jd = 0; jd < 4; ++jd) {
        bf16x4 o4;
#pragma unroll
        for (int rr = 0; rr < 4; ++rr) o4[rr] = (bf16)oacc[jd][rr];
        *(bf16x4*)&Opart[(size_t)qRow * 1024 + hOff + jd * 16 + quad * 4] = o4;
    }
    if (quad == 0) {
        float* p = fa.ml + ((size_t)(s * 2048 + qRow) * 16 + h) * 2;
        p[0] = m_i;   // log2 domain
        p[1] = l_i;
    }
}

// ---------------------------------------------------------------------------
// Combine the split partials: one wave per (row, head), lane = d.
// m/l are in log2 domain -> exp2. Blocks 0..7 also zero the proj
// sum-of-squares accumulator (region dead between g1 and p1).
// ---------------------------------------------------------------------------
struct CombArgs {
    const bf16* op[NSPLIT];
    const float* ml;
    bf16* ctx;
    float* ssp;  // 2048 floats, zeroed by blocks 0..7
};
__global__ __launch_bounds__(256) void combine_kernel(CombArgs ca) {
    if (blockIdx.x < 8) ca.ssp[blockIdx.x * 256 + threadIdx.x] = 0.0f;
    const int unit = blockIdx.x * 4 + (threadIdx.x >> 6);
    const int row = unit >> 4, h = unit & 15;
    const int d = threadIdx.x & 63;
    float mv[NSPLIT], lv[NSPLIT], M = -1e30f;
#pragma unroll
    for (int s2 = 0; s2 < NSPLIT; ++s2) {
        const float* p = ca.ml + ((size_t)(s2 * 2048 + row) * 16 + h) * 2;
        mv[s2] = p[0];
        lv[s2] = p[1];
        M = fmaxf(M, mv[s2]);
    }
    float num = 0.0f, den = 0.0f;
#pragma unroll
    for (int s2 = 0; s2 < NSPLIT; ++s2) {
        float e = fexp2(mv[s2] - M);
        den += lv[s2] * e;
        num += e * (float)ca.op[s2][(size_t)row * 1024 + h * 64 + d];
    }
    ca.ctx[(size_t)row * 1024 + h * 64 + d] = (bf16)(num / den);
}

// ---------------------------------------------------------------------------
// Orchestration. Inputs/outputs FLOAT32 per the reference. 7 launches:
// prep -> g1 -> g2 -> flash -> combine -> p1 -> p2.  (R7/R15 structure,
// best harness-verified configuration: 208.3us.)
// ws layout (40 MB, phase-aliased):
//   0..4M    xb -> qb                16..24M  kb16[0..3] (kb16[3]=proj key)
//   4..12M   g3[0,1] -> Opart s0,s1  24..32M  vT16[0..3] (vT16[3]=proj val)
//   12..16M  g3[2] (dead post-g2)
//   20..21M  kb16[2] (dead) -> ml    21..21M+8K  SSp (zeroed by combine)
//   32..36M  kbuf -> ctx             36..40M  VtG (g2 z=2 epilogue)
//   projg aliases 4..8M after combine.
// SSq (3x2048 f32) lives in d_out (dead until p2 writes), zeroed by prep.
// ---------------------------------------------------------------------------
extern "C" void kernel_launch(void* const* d_in, const int* in_sizes, int n_in,
                              void* d_out, int out_size, void* d_ws,
                              size_t ws_size, hipStream_t stream) {
    const float* x = (const float*)d_in[0];
    const float* keysF[4] = {(const float*)d_in[1], (const float*)d_in[3],
                             (const float*)d_in[5], (const float*)d_in[7]};
    const float* valsF[4] = {(const float*)d_in[2], (const float*)d_in[4],
                             (const float*)d_in[6], (const float*)d_in[8]};
    float* out = (float*)d_out;

    char* ws = (char*)d_ws;
    bf16* xb = (bf16*)(ws);
    bf16* g3[3];
    for (int i = 0; i < 3; ++i) g3[i] = (bf16*)(ws + (4ull << 20) + (size_t)i * (4ull << 20));
    bf16* kb16[4], *vT16[4];
    for (int i = 0; i < 4; ++i) {
        kb16[i] = (bf16*)(ws + (16ull << 20) + (size_t)i * (2ull << 20));
        vT16[i] = (bf16*)(ws + (24ull << 20) + (size_t)i * (2ull << 20));
    }
    bf16* qb    = (bf16*)(ws);
    bf16* kbuf  = (bf16*)(ws + (32ull << 20));
    float* mlbuf = (float*)(ws + (20ull << 20));
    bf16* VtG   = (bf16*)(ws + (36ull << 20));
    bf16* ctx   = (bf16*)(ws + (32ull << 20));
    bf16* projg = (bf16*)(ws + (4ull << 20));

    float* SSq = (float*)d_out;                 // 3x2048 f32 (out: dead til p2)
    float* SSp = (float*)(ws + (21ull << 20));  // 2048 f32 (dead zone 21..22M)

    bf16* opart[NSPLIT];
    for (int i = 0; i < NSPLIT; ++i)
        opart[i] = (bf16*)(ws + (4ull << 20) + (size_t)i * (4ull << 20));

    // 1. merged prep: convert x + 4 keys; transpose+convert 4 vals; zero SSq
    PrepArgs pa;
    pa.csrc[0] = x;             pa.cdst[0] = xb;
    pa.csrc[1] = x + (1 << 20); pa.cdst[1] = xb + (1 << 20);
    for (int i = 0; i < 4; ++i) { pa.csrc[2 + i] = keysF[i]; pa.cdst[2 + i] = kb16[i]; }
    for (int i = 0; i < 4; ++i) { pa.tsrc[i] = valsF[i]; pa.tdst[i] = vT16[i]; }
    pa.ssq = SSq;
    prep_kernel<<<dim3(1024, 10), 256, 0, stream>>>(pa);

    // 2. batched QKV: g = gelu(x @ key^T), fused row sum-of-squares -> SSq
    GemmArgs<1, bf16> g1;
    for (int z = 0; z < 3; ++z) {
        g1.A[z] = xb; g1.B[z] = kb16[z]; g1.C[z] = g3[z];
        g1.S[z] = SSq + z * 2048; g1.Ct[z] = nullptr; g1.emul[z] = 1.0f;
    }
    gemm_bt<1, bf16><<<dim3(16, 16, 3), 256, 0, stream>>>(g1);

    // 3. batched: q (with 0.125*log2e baked in), k row-major; V written
    //    directly transposed+swizzled (VtG). Scale = 32*rsqrt(SSq[row]).
    GemmArgs<2, bf16> g2;
    bf16* qkv[3] = {qb, kbuf, qb /*unused for z=2*/};
    for (int z = 0; z < 3; ++z) {
        g2.A[z] = g3[z]; g2.B[z] = vT16[z]; g2.C[z] = qkv[z];
        g2.S[z] = SSq + z * 2048;
        g2.Ct[z] = (z == 2) ? VtG : nullptr;
        g2.emul[z] = (z == 0) ? QSCALE_LOG2E : 1.0f;
    }
    gemm_bt<2, bf16><<<dim3(16, 16, 3), 256, 0, stream>>>(g2);

    // 4. flash attention: 1024 blocks x 256 thr, 2-phase pipelined LDS
    FlashArgs fla;
    fla.Q = qb; fla.K = kbuf; fla.VtG = VtG; fla.ml = mlbuf;
    for (int i = 0; i < NSPLIT; ++i) fla.op[i] = opart[i];
    flash_kernel<<<dim3(1024), 256, 0, stream>>>(fla);

    // 5. combine split partials -> ctx (also zeroes SSp)
    CombArgs cba;
    for (int i = 0; i < NSPLIT; ++i) cba.op[i] = opart[i];
    cba.ml = mlbuf; cba.ctx = ctx; cba.ssp = SSp;
    combine_kernel<<<dim3(8192), 256, 0, stream>>>(cba);

    // 6-7. output projection pattention (64x64-tile GEMMs, 2 blocks/CU)
    GemmArgs<1, bf16> p1;
    for (int z = 0; z < 3; ++z) {
        p1.A[z] = ctx; p1.B[z] = kb16[3]; p1.C[z] = projg;
        p1.S[z] = SSp; p1.Ct[z] = nullptr; p1.emul[z] = 1.0f;
    }
    gemm_bt64<1, bf16><<<dim3(16, 32, 1), 256, 0, stream>>>(p1);

    GemmArgs<2, float> p2;
    for (int z = 0; z < 3; ++z) {
        p2.A[z] = projg; p2.B[z] = vT16[3]; p2.C[z] = out;
        p2.S[z] = SSp; p2.Ct[z] = nullptr; p2.emul[z] = 1.0f;
    }
    gemm_bt64<2, float><<<dim3(16, 32, 1), 256, 0, stream>>>(p2);
}